// Round 2
// baseline (410.059 us; speedup 1.0000x reference)
//
#include <hip/hip_runtime.h>
#include <cstdint>
#include <cstddef>

typedef unsigned short u16;
typedef short v8s __attribute__((ext_vector_type(8)));
typedef float v4f __attribute__((ext_vector_type(4)));

constexpr int SEQ = 4096;
constexpr int FEAT = 2048;
constexpr int F3 = 6144;

// ---------- helpers ----------

__device__ __forceinline__ u16 f2bf(float f) {
  union { float f; uint32_t u; } v; v.f = f;
  uint32_t r = v.u + 0x7FFFu + ((v.u >> 16) & 1u);  // round-to-nearest-even
  return (u16)(r >> 16);
}

__device__ __forceinline__ float bf2f(u16 s) {
  union { uint32_t u; float f; } v; v.u = ((uint32_t)s) << 16;
  return v.f;
}

// async global->LDS, 16B per lane; lds dest is wave-uniform base (HW: base+lane*16)
__device__ __forceinline__ void gld_lds16(const u16* g, u16* l) {
  __builtin_amdgcn_global_load_lds(
      (const __attribute__((address_space(1))) void*)g,
      (__attribute__((address_space(3))) void*)l, 16, 0, 0);
}

// ---------- conversion / transpose ----------

__global__ void cvt_f32_bf16(const float* __restrict__ in, u16* __restrict__ out, int n8) {
  int i = blockIdx.x * 256 + threadIdx.x;
  if (i >= n8) return;
  const float4* p = (const float4*)in + (size_t)i * 2;
  float4 a = p[0], b = p[1];
  union { u16 s[8]; uint4 v; } u;
  u.s[0] = f2bf(a.x); u.s[1] = f2bf(a.y); u.s[2] = f2bf(a.z); u.s[3] = f2bf(a.w);
  u.s[4] = f2bf(b.x); u.s[5] = f2bf(b.y); u.s[6] = f2bf(b.z); u.s[7] = f2bf(b.w);
  *(uint4*)(out + (size_t)i * 8) = u.v;
}

__global__ void transp_f2b(const float* __restrict__ in, int ldin,
                           u16* __restrict__ out, int ldout) {
  __shared__ float tile[32][33];
  int c0 = blockIdx.x * 32, r0 = blockIdx.y * 32;
  int tx = threadIdx.x, ty = threadIdx.y;
#pragma unroll
  for (int p = 0; p < 4; ++p)
    tile[ty + 8 * p][tx] = in[(size_t)(r0 + ty + 8 * p) * ldin + c0 + tx];
  __syncthreads();
#pragma unroll
  for (int p = 0; p < 4; ++p)
    out[(size_t)(c0 + ty + 8 * p) * ldout + r0 + tx] = f2bf(tile[tx][ty + 8 * p]);
}

__global__ void transp_b2b(const u16* __restrict__ in, int ldin,
                           u16* __restrict__ out, int ldout) {
  __shared__ u16 tile[32][33];
  int c0 = blockIdx.x * 32, r0 = blockIdx.y * 32;
  int tx = threadIdx.x, ty = threadIdx.y;
#pragma unroll
  for (int p = 0; p < 4; ++p)
    tile[ty + 8 * p][tx] = in[(size_t)(r0 + ty + 8 * p) * ldin + c0 + tx];
  __syncthreads();
#pragma unroll
  for (int p = 0; p < 4; ++p)
    out[(size_t)(c0 + ty + 8 * p) * ldout + r0 + tx] = tile[tx][ty + 8 * p];
}

// ---------- gemmw: C[M,N] = A[M,K] * B[N,K]^T  (bf16 in, k contiguous) ----------
// Tile 128x256, BK=32, 512 thr = 8 waves (2M x 4N, 64x64 per wave), 16x16x32 MFMA.
// LDS: 3-buffer rotation (A 3x8KB + B 3x16KB = 72 KiB) -> with <=128 regs/wave
// (__launch_bounds__(512,4)) gives 2 blocks/CU: co-resident blocks fill each
// other's barrier/LDS stalls (m97/m114 mechanism).
// Per phase (one 32-K tile): 8 ds_read_b128 -> stage tile t+2 (3 global_load_lds)
// -> 16 MFMA -> s_waitcnt vmcnt(3) -> ONE s_barrier.
// Race-safety: stage at phase t targets buf[(t+2)%3] (= tile t-1's buffer,
// last read in phase t-1, protected by the end-of-(t-1) barrier). Reads at t
// use data staged at t-2, landed per vmcnt(3)+barrier at end of t-1.
// LDS swizzle (proven in the old 128^2 kernel: conflicts 1.26e7 -> 0): row of
// 32 elems = 4 chunks of 16B; logical chunk c stored at (c + (row>>1))&3;
// global source pre-rotated (both-sides rule).
// CAUSAL mode (att@v): grid (N/256, M/128, 2); z=1 flips bi -> gridDim.y-1-bi
// so the two blocks a CU hosts have complementary K-depths (constant sum);
// K-range z*(bi+1)*64 .. (z+1)*(bi+1)*64; fp32 atomicAdd output.

#define BAR()  asm volatile("s_barrier" ::: "memory")
#define VMC3() asm volatile("s_waitcnt vmcnt(3)" ::: "memory")

template<int LDA, int LDB, int LDC, int OUTMODE /*0=bf16 store, 1=fp32 atomicAdd*/,
         int ADDB, int CAUSAL, int SWZ>
__global__ __launch_bounds__(512, 4) void gemmw(
    const u16* __restrict__ A, const u16* __restrict__ B,
    void* __restrict__ Cv, int K,
    const float* __restrict__ bias, float scale) {
  int bi, bj;
  if (SWZ) {
    const int gx = gridDim.x;
    const int nwg = gx * gridDim.y;           // multiple of 8 for both GEMM grids
    const int b = blockIdx.y * gx + blockIdx.x;
    const int cpx = nwg >> 3;
    const int s = (b & 7) * cpx + (b >> 3);   // bijective: nwg % 8 == 0
    bj = s % gx;  bi = s / gx;
  } else { bj = blockIdx.x; bi = blockIdx.y; }
  int ks, ke;
  if (CAUSAL) {
    if (blockIdx.z) bi = (int)gridDim.y - 1 - bi;   // complementary pairing
    const int kq = (bi + 1) * 64;
    ks = blockIdx.z ? kq : 0;  ke = ks + kq;        // multiple of 64 -> nt>=2
  } else { ks = 0; ke = K; }
  const int i0 = bi * 128, j0 = bj * 256;

  __shared__ u16 As[3][4096];   // [buf][128 rows x 32], 8 KiB each
  __shared__ u16 Bs[3][8192];   // [buf][256 rows x 32], 16 KiB each

  const int t = threadIdx.x;
  const int w = t >> 6, l = t & 63;
  const int wr = w >> 2, wc = w & 3;
  const int lm = l & 15, lq = l >> 4;
  // fragment read: physical chunk = (lq + (row>>1)) & 3; row>>1 mod 4 == (lm>>1)&3
  const int lqs = ((lq + (lm >> 1)) & 3) * 8;

  // staging: thread covers chunk c = w*64+l (+512 per extra instr); row = t>>2,
  // physical chunk = t&3, logical = ((t&3) - ((t>>3)&3)) & 3 (swizzle inverse)
  const int srow = t >> 2;
  const int scol = (((t & 3) - ((t >> 3) & 3)) & 3) * 8;
  const u16* Ag = A + (size_t)(i0 + srow) * LDA + scol;
  const u16* Bg = B + (size_t)(j0 + srow) * LDB + scol;
  u16* Al = &As[0][0] + w * 512;   // + buf*4096 elems
  u16* Bl = &Bs[0][0] + w * 512;   // + buf*8192 elems

  v4f acc[4][4];
#pragma unroll
  for (int a = 0; a < 4; ++a)
#pragma unroll
    for (int b2 = 0; b2 < 4; ++b2)
      acc[a][b2] = v4f{0.f, 0.f, 0.f, 0.f};

  // prologue: stage tiles 0 (buf0) and 1 (buf1); vmcnt(3) -> tile0 landed
  gld_lds16(Ag + ks, Al);
  gld_lds16(Bg + ks, Bl);
  gld_lds16(Bg + 128 * LDB + ks, Bl + 4096);
  gld_lds16(Ag + ks + 32, Al + 4096);
  gld_lds16(Bg + ks + 32, Bl + 8192);
  gld_lds16(Bg + 128 * LDB + ks + 32, Bl + 8192 + 4096);
  VMC3(); BAR();

  const int nt = (ke - ks) >> 5;   // >= 2 always
  int bufr = 0;
  int k2 = ks + 64;                // k-offset of tile t+2
  for (int tt = 0; tt < nt; ++tt) {
    // ds-load this tile's fragments (8 x ds_read_b128)
    v8s af[4], bf4[4];
    const u16* Ar = &As[0][0] + bufr * 4096 + (wr * 64 + lm) * 32 + lqs;
    const u16* Br = &Bs[0][0] + bufr * 8192 + (wc * 64 + lm) * 32 + lqs;
#pragma unroll
    for (int mi = 0; mi < 4; ++mi) af[mi] = *(const v8s*)(Ar + mi * 512);
#pragma unroll
    for (int ni = 0; ni < 4; ++ni) bf4[ni] = *(const v8s*)(Br + ni * 512);
    // stage tile tt+2 into buf (bufr+2)%3 (holds tile tt-1: freed by prev barrier)
    const int sb = (bufr + 2 >= 3) ? bufr - 1 : bufr + 2;
    const int kst = (k2 < ke) ? k2 : ks;   // clamped stages are never read
    gld_lds16(Ag + kst, Al + sb * 4096);
    gld_lds16(Bg + kst, Bl + sb * 8192);
    gld_lds16(Bg + 128 * LDB + kst, Bl + sb * 8192 + 4096);
    // 16 MFMA (compiler inserts the lgkmcnt for af/bf4)
    __builtin_amdgcn_s_setprio(1);
#pragma unroll
    for (int mi = 0; mi < 4; ++mi)
#pragma unroll
      for (int ni = 0; ni < 4; ++ni)
        acc[mi][ni] = __builtin_amdgcn_mfma_f32_16x16x32_bf16(af[mi], bf4[ni], acc[mi][ni], 0, 0, 0);
    __builtin_amdgcn_s_setprio(0);
    VMC3(); BAR();                 // tile tt+1 landed; all waves done reading tile tt
    bufr = (bufr == 2) ? 0 : bufr + 1;
    k2 += 32;
  }

  // epilogue: C/D layout col=lane&15, row=quad*4+reg [m89-verified]
#pragma unroll
  for (int mi = 0; mi < 4; ++mi) {
#pragma unroll
    for (int ni = 0; ni < 4; ++ni) {
      const int cc = j0 + wc * 64 + ni * 16 + lm;
      const float badd = ADDB ? bias[cc] : 0.f;
#pragma unroll
      for (int r = 0; r < 4; ++r) {
        const int rr = i0 + wr * 64 + mi * 16 + lq * 4 + r;
        if (OUTMODE == 0)
          ((u16*)Cv)[(size_t)rr * LDC + cc] = f2bf(acc[mi][ni][r] * scale + badd);
        else
          atomicAdd((float*)Cv + (size_t)rr * LDC + cc, acc[mi][ni][r]);
      }
    }
  }
}

// ---------- row softmax with causal + padding mask (single bf16 input) ----------
__global__ __launch_bounds__(256) void softmax_rows(
    const u16* __restrict__ S0,
    u16* __restrict__ att, const int* __restrict__ npad_p) {
  const int i = blockIdx.x;
  const int np = *npad_p;
  const int kend = ((i >> 7) + 1) << 7;   // 128-rounded: matches attV read range
  const u16* r0 = S0 + (size_t)i * SEQ;
  u16* arow = att + (size_t)i * SEQ;
  const int t = threadIdx.x;

  float m = -3.0e38f, s = 0.f;
  for (int j = np + t; j <= i; j += 256) {
    float v = bf2f(r0[j]);
    if (v > m) { s = s * __expf(m - v) + 1.f; m = v; }
    else       { s += __expf(v - m); }
  }
#pragma unroll
  for (int off = 32; off > 0; off >>= 1) {
    float mo = __shfl_xor(m, off);
    float so = __shfl_xor(s, off);
    float M = fmaxf(m, mo);
    s = s * __expf(m - M) + so * __expf(mo - M);
    m = M;
  }
  __shared__ float sm[4], ss[4];
  const int w = t >> 6, l = t & 63;
  if (l == 0) { sm[w] = m; ss[w] = s; }
  __syncthreads();
  const float M = fmaxf(fmaxf(sm[0], sm[1]), fmaxf(sm[2], sm[3]));
  const float Ssum = ss[0] * __expf(sm[0] - M) + ss[1] * __expf(sm[1] - M) +
                     ss[2] * __expf(sm[2] - M) + ss[3] * __expf(sm[3] - M);
  const float inv = 1.f / Ssum;  // padded rows masked to 0 below; inv unused there

  for (int j0b = t * 8; j0b < kend; j0b += 2048) {
    union { u16 s8[8]; uint4 v; } u;
#pragma unroll
    for (int q = 0; q < 8; ++q) {
      const int j = j0b + q;
      float a = 0.f;
      if (j >= np && j <= i)
        a = __expf(bf2f(r0[j]) - M) * inv;
      u.s8[q] = f2bf(a);
    }
    *(uint4*)(arow + j0b) = u.v;
  }
}

// ---------- launch ----------

extern "C" void kernel_launch(void* const* d_in, const int* in_sizes, int n_in,
                              void* d_out, int out_size, void* d_ws, size_t ws_size,
                              hipStream_t stream) {
  const float* x = (const float*)d_in[0];
  const float* W = (const float*)d_in[1];
  const float* b = (const float*)d_in[2];
  const int* npad = (const int*)d_in[3];
  float* out = (float*)d_out;

  // workspace:
  // [xb 16MB | Wt 24MB] reused as att 32MB ][ qkvb 48MB ][ vt 16MB ][ sc0 32MB ]
  char* p = (char*)d_ws;
  u16* xb = (u16*)p;
  u16* Wt = (u16*)(p + (size_t)SEQ * FEAT * 2);
  u16* att = (u16*)p;
  p += (size_t)SEQ * FEAT * 2 + (size_t)F3 * FEAT * 2;
  u16* qkvb = (u16*)p;  p += (size_t)SEQ * F3 * 2;
  u16* vt   = (u16*)p;  p += (size_t)FEAT * SEQ * 2;
  u16* sc0  = (u16*)p;  p += (size_t)SEQ * SEQ * 2;   // bf16 scores (full rows)
  if (ws_size < (size_t)(p - (char*)d_ws)) return;

  const float scale = 0.02209708691207961f;  // 1/sqrt(2048)

  // zero d_out (att@v split-K atomically accumulates into it)
  hipMemsetAsync(d_out, 0, (size_t)SEQ * FEAT * sizeof(float), stream);

  cvt_f32_bf16<<<SEQ * FEAT / 8 / 256, 256, 0, stream>>>(x, xb, SEQ * FEAT / 8);
  transp_f2b<<<dim3(F3 / 32, FEAT / 32), dim3(32, 8), 0, stream>>>(W, F3, Wt, FEAT);
  // qkv = x @ W + b: 128x256 tiles, grid 24x32 = 768 blocks (2 blocks/CU co-res)
  gemmw<FEAT, FEAT, F3, 0, 1, 0, 1><<<dim3(F3 / 256, SEQ / 128), 512, 0, stream>>>(
      xb, Wt, (void*)qkvb, FEAT, b, 1.0f);
  transp_b2b<<<dim3(FEAT / 32, SEQ / 32), dim3(32, 8), 0, stream>>>(
      qkvb + 2 * FEAT, F3, vt, SEQ);
  // scores = (q @ k^T)/sqrt(F): grid 16x32 = 512 blocks (exactly 2/CU)
  gemmw<F3, F3, SEQ, 0, 0, 0, 1><<<dim3(SEQ / 256, SEQ / 128), 512, 0, stream>>>(
      qkvb, qkvb + FEAT, (void*)sc0, FEAT, nullptr, scale);
  softmax_rows<<<SEQ, 256, 0, stream>>>(sc0, att, npad);
  // out = att @ v: causal, split-K z=2 with complementary bi pairing, fp32 atomic
  gemmw<SEQ, SEQ, FEAT, 1, 0, 1, 0><<<dim3(FEAT / 256, SEQ / 128, 2), 512, 0, stream>>>(
      att, vt, (void*)out, 0, nullptr, 1.0f);
}

// Round 3
// 401.895 us; speedup vs baseline: 1.0203x; 1.0203x over previous
//
#include <hip/hip_runtime.h>
#include <cstdint>
#include <cstddef>
#include <cmath>

typedef unsigned short u16;
typedef short v8s __attribute__((ext_vector_type(8)));
typedef float v4f __attribute__((ext_vector_type(4)));

constexpr int SEQ = 4096;
constexpr int FEAT = 2048;
constexpr int F3 = 6144;

// ---------- helpers ----------

__device__ __forceinline__ u16 f2bf(float f) {
  union { float f; uint32_t u; } v; v.f = f;
  uint32_t r = v.u + 0x7FFFu + ((v.u >> 16) & 1u);  // round-to-nearest-even
  return (u16)(r >> 16);
}

__device__ __forceinline__ float bf2f(u16 s) {
  union { uint32_t u; float f; } v; v.u = ((uint32_t)s) << 16;
  return v.f;
}

// async global->LDS, 16B per lane; lds dest is wave-uniform base (HW: base+lane*16)
__device__ __forceinline__ void gld_lds16(const u16* g, u16* l) {
  __builtin_amdgcn_global_load_lds(
      (const __attribute__((address_space(1))) void*)g,
      (__attribute__((address_space(3))) void*)l, 16, 0, 0);
}

// ---------- conversion / transpose ----------

__global__ void cvt_f32_bf16(const float* __restrict__ in, u16* __restrict__ out, int n8) {
  int i = blockIdx.x * 256 + threadIdx.x;
  if (i >= n8) return;
  const float4* p = (const float4*)in + (size_t)i * 2;
  float4 a = p[0], b = p[1];
  union { u16 s[8]; uint4 v; } u;
  u.s[0] = f2bf(a.x); u.s[1] = f2bf(a.y); u.s[2] = f2bf(a.z); u.s[3] = f2bf(a.w);
  u.s[4] = f2bf(b.x); u.s[5] = f2bf(b.y); u.s[6] = f2bf(b.z); u.s[7] = f2bf(b.w);
  *(uint4*)(out + (size_t)i * 8) = u.v;
}

__global__ void transp_f2b(const float* __restrict__ in, int ldin,
                           u16* __restrict__ out, int ldout) {
  __shared__ float tile[32][33];
  int c0 = blockIdx.x * 32, r0 = blockIdx.y * 32;
  int tx = threadIdx.x, ty = threadIdx.y;
#pragma unroll
  for (int p = 0; p < 4; ++p)
    tile[ty + 8 * p][tx] = in[(size_t)(r0 + ty + 8 * p) * ldin + c0 + tx];
  __syncthreads();
#pragma unroll
  for (int p = 0; p < 4; ++p)
    out[(size_t)(c0 + ty + 8 * p) * ldout + r0 + tx] = f2bf(tile[tx][ty + 8 * p]);
}

__global__ void transp_b2b(const u16* __restrict__ in, int ldin,
                           u16* __restrict__ out, int ldout) {
  __shared__ u16 tile[32][33];
  int c0 = blockIdx.x * 32, r0 = blockIdx.y * 32;
  int tx = threadIdx.x, ty = threadIdx.y;
#pragma unroll
  for (int p = 0; p < 4; ++p)
    tile[ty + 8 * p][tx] = in[(size_t)(r0 + ty + 8 * p) * ldin + c0 + tx];
  __syncthreads();
#pragma unroll
  for (int p = 0; p < 4; ++p)
    out[(size_t)(c0 + ty + 8 * p) * ldout + r0 + tx] = tile[tx][ty + 8 * p];
}

// ---------- gemmw: C[M,N] = A[M,K] * B[N,K]^T  (bf16 in, k contiguous) ----------
// Tile 128x128, BK=32, 256 thr = 4 waves (2x2 of 64x64), 16x16x32 MFMA.
// LDS: 3-buffer rotation (A 3x8KB + B 3x8KB = 48 KiB) + __launch_bounds__(256,3)
// -> 3 blocks/CU (12 waves): co-resident blocks fill each other's stalls.
// Register-double-buffered phase, ONE barrier per 32-K tile:
//   phase t: STAGE(t+2) | A-read(t) (4 ds_read_b128) | MFMA(t)x16
//            (af in-phase, bf pre-loaded) | vmcnt(4) | s_barrier | B-read(t+1)->regs
// Race-safety:
//  - all waves pass their own vmcnt(4) (leaves only this phase's 4 stages in
//    flight) BEFORE the barrier => after the barrier tile t+1 is fully in LDS
//    for ALL waves => post-barrier B-read(t+1) safe.
//  - STAGE(t+2) overwrites tile t-1's buffer; its last reads (A at phase t-1,
//    B at end of phase t-2) are lgkm-drained by MFMA operand waits before
//    their wave crosses BAR(t-1), which precedes the stage. 
//  - MFMA(t)'s af reads come after BAR(t-1), whose vmcnt(4) guaranteed tile t.
// LDS swizzle (proven: conflicts 1.26e7 -> 0): row of 32 elems = 4 chunks of
// 16B; logical chunk c stored at (c + (row>>1))&3; global source pre-rotated.
// MODE (CAUSAL param): 0 = full grid; 1 = causal split-K z=2 for att@v
// (K-range z*(bi+1)*64..., z=1 flips bi for complementary pairing, fp32
// atomicAdd); 2 = compact lower-triangular grid (scores q@k^T).

#define BARW()  asm volatile("s_barrier" ::: "memory")
#define VMC4() asm volatile("s_waitcnt vmcnt(4)" ::: "memory")

#define STAGE(SB, KO) do { \
  gld_lds16(Ag + (KO), &As[SB][0] + w * 512); \
  gld_lds16(Ag + (size_t)64 * LDA_ + (KO), &As[SB][0] + w * 512 + 2048); \
  gld_lds16(Bg + (KO), &Bs[SB][0] + w * 512); \
  gld_lds16(Bg + (size_t)64 * LDB_ + (KO), &Bs[SB][0] + w * 512 + 2048); \
} while (0)

#define LOADA(BUF) do { _Pragma("unroll") \
  for (int mi = 0; mi < 4; ++mi) \
    af[mi] = *(const v8s*)(&As[BUF][0] + (wr * 64 + mi * 16 + lm) * 32 + lqs); \
} while (0)

#define LOADB(BUF) do { _Pragma("unroll") \
  for (int ni = 0; ni < 4; ++ni) \
    bf4[ni] = *(const v8s*)(&Bs[BUF][0] + (wc * 64 + ni * 16 + lm) * 32 + lqs); \
} while (0)

template<int LDA_, int LDB_, int LDC_, int OUTMODE /*0=bf16 store, 1=fp32 atomicAdd*/,
         int ADDB, int CAUSAL, int SWZ>
__global__ __launch_bounds__(256, 3) void gemmw(
    const u16* __restrict__ A, const u16* __restrict__ B,
    void* __restrict__ Cv, int K,
    const float* __restrict__ bias, float scale) {
  int bi, bj, ks, ke;
  if (CAUSAL == 2) {
    // compact lower-triangular grid (bj <= bi), XCD-chunked (nwg % 8 == 0)
    const int b = blockIdx.x;
    const int cpx = gridDim.x >> 3;
    const int s = (b & 7) * cpx + (b >> 3);
    bi = (int)((sqrtf(8.f * s + 1.f) - 1.f) * 0.5f);
    while ((bi + 1) * (bi + 2) / 2 <= s) ++bi;
    while (bi * (bi + 1) / 2 > s) --bi;
    bj = s - bi * (bi + 1) / 2;
    ks = 0; ke = K;
  } else if (CAUSAL == 1) {
    bi = blockIdx.y; bj = blockIdx.x;
    if (blockIdx.z) bi = (int)gridDim.y - 1 - bi;   // complementary pairing
    const int kq = (bi + 1) * 64;
    ks = blockIdx.z ? kq : 0;  ke = ks + kq;        // nt = 2*(bi+1) >= 2
  } else {
    if (SWZ) {
      // column-major within XCD chunk: same-XCD neighbors share the B panel
      const int gx = gridDim.x, gy = gridDim.y;
      const int b = blockIdx.y * gx + blockIdx.x;
      const int cpx = (gx * gy) >> 3;               // nwg % 8 == 0
      const int s = (b & 7) * cpx + (b >> 3);
      bi = s % gy;  bj = s / gy;
    } else { bj = blockIdx.x; bi = blockIdx.y; }
    ks = 0; ke = K;
  }
  const int i0 = bi * 128, j0 = bj * 128;

  __shared__ u16 As[3][4096];   // [buf][128 rows x 32], 8 KiB each
  __shared__ u16 Bs[3][4096];

  const int t = threadIdx.x;
  const int w = t >> 6, l = t & 63;
  const int wr = w >> 1, wc = w & 1;
  const int lm = l & 15, lq = l >> 4;
  // fragment read: physical chunk = (lq + (row>>1)) & 3 -> (lq + (lm>>1)) & 3
  const int lqs = ((lq + (lm >> 1)) & 3) * 8;

  // staging: thread covers chunks c = t (rows 0..63) and c = t+256 (rows 64..127,
  // same col offset); row = t>>2, logical chunk = ((t&3) - ((t>>3)&3)) & 3
  const int srow = t >> 2;
  const int scol = (((t & 3) - ((t >> 3) & 3)) & 3) * 8;
  const u16* Ag = A + (size_t)(i0 + srow) * LDA_ + scol;
  const u16* Bg = B + (size_t)(j0 + srow) * LDB_ + scol;

  v4f acc[4][4];
#pragma unroll
  for (int a = 0; a < 4; ++a)
#pragma unroll
    for (int b2 = 0; b2 < 4; ++b2)
      acc[a][b2] = v4f{0.f, 0.f, 0.f, 0.f};

  v8s af[4], bf4[4];

  // prologue: stage tiles 0 (buf0) and 1 (buf1); vmcnt(4) -> tile0 landed
  STAGE(0, ks); STAGE(1, ks + 32);
  VMC4(); BARW();
  LOADB(0);                           // B fragments of tile 0 -> regs

  const int nt = (ke - ks) >> 5;      // >= 2 always
  int bufr = 0;
  int k2 = ks + 64;                   // k-offset of tile t+2
  for (int tt = 0; tt < nt; ++tt) {
    const int sb = (bufr + 2 >= 3) ? bufr - 1 : bufr + 2;
    const int kst = (k2 < ke) ? k2 : ks;   // clamped stages are never read
    STAGE(sb, kst);
    LOADA(bufr);                      // 4 ds_read_b128, in-phase
    __builtin_amdgcn_s_setprio(1);
#pragma unroll
    for (int mi = 0; mi < 4; ++mi)
#pragma unroll
      for (int ni = 0; ni < 4; ++ni)
        acc[mi][ni] = __builtin_amdgcn_mfma_f32_16x16x32_bf16(af[mi], bf4[ni], acc[mi][ni], 0, 0, 0);
    __builtin_amdgcn_s_setprio(0);
    VMC4(); BARW();                   // tile tt+1 landed (all waves)
    const int nb = (bufr == 2) ? 0 : bufr + 1;
    LOADB(nb);                        // B fragments of tile tt+1 -> regs
    bufr = nb;
    k2 += 32;
  }

  // epilogue: C/D layout col=lane&15, row=quad*4+reg [m89-verified]
#pragma unroll
  for (int mi = 0; mi < 4; ++mi) {
#pragma unroll
    for (int ni = 0; ni < 4; ++ni) {
      const int cc = j0 + wc * 64 + ni * 16 + lm;
      const float badd = ADDB ? bias[cc] : 0.f;
#pragma unroll
      for (int r = 0; r < 4; ++r) {
        const int rr = i0 + wr * 64 + mi * 16 + lq * 4 + r;
        if (OUTMODE == 0)
          ((u16*)Cv)[(size_t)rr * LDC_ + cc] = f2bf(acc[mi][ni][r] * scale + badd);
        else
          atomicAdd((float*)Cv + (size_t)rr * LDC_ + cc, acc[mi][ni][r]);
      }
    }
  }
}

// ---------- row softmax with causal + padding mask (single bf16 input) ----------
__global__ __launch_bounds__(256) void softmax_rows(
    const u16* __restrict__ S0,
    u16* __restrict__ att, const int* __restrict__ npad_p) {
  const int i = blockIdx.x;
  const int np = *npad_p;
  const int kend = ((i >> 7) + 1) << 7;   // 128-rounded: matches attV read range
  const u16* r0 = S0 + (size_t)i * SEQ;
  u16* arow = att + (size_t)i * SEQ;
  const int t = threadIdx.x;

  float m = -3.0e38f, s = 0.f;
  for (int j = np + t; j <= i; j += 256) {
    float v = bf2f(r0[j]);
    if (v > m) { s = s * __expf(m - v) + 1.f; m = v; }
    else       { s += __expf(v - m); }
  }
#pragma unroll
  for (int off = 32; off > 0; off >>= 1) {
    float mo = __shfl_xor(m, off);
    float so = __shfl_xor(s, off);
    float M = fmaxf(m, mo);
    s = s * __expf(m - M) + so * __expf(mo - M);
    m = M;
  }
  __shared__ float sm[4], ss[4];
  const int w = t >> 6, l = t & 63;
  if (l == 0) { sm[w] = m; ss[w] = s; }
  __syncthreads();
  const float M = fmaxf(fmaxf(sm[0], sm[1]), fmaxf(sm[2], sm[3]));
  const float Ssum = ss[0] * __expf(sm[0] - M) + ss[1] * __expf(sm[1] - M) +
                     ss[2] * __expf(sm[2] - M) + ss[3] * __expf(sm[3] - M);
  const float inv = 1.f / Ssum;  // padded rows masked to 0 below; inv unused there

  for (int j0b = t * 8; j0b < kend; j0b += 2048) {
    union { u16 s8[8]; uint4 v; } u;
#pragma unroll
    for (int q = 0; q < 8; ++q) {
      const int j = j0b + q;
      float a = 0.f;
      if (j >= np && j <= i)
        a = __expf(bf2f(r0[j]) - M) * inv;
      u.s8[q] = f2bf(a);
    }
    *(uint4*)(arow + j0b) = u.v;
  }
}

// ---------- launch ----------

extern "C" void kernel_launch(void* const* d_in, const int* in_sizes, int n_in,
                              void* d_out, int out_size, void* d_ws, size_t ws_size,
                              hipStream_t stream) {
  const float* x = (const float*)d_in[0];
  const float* W = (const float*)d_in[1];
  const float* b = (const float*)d_in[2];
  const int* npad = (const int*)d_in[3];
  float* out = (float*)d_out;

  // workspace:
  // [xb 16MB | Wt 24MB] reused as att 32MB ][ qkvb 48MB ][ vt 16MB ][ sc0 32MB ]
  char* p = (char*)d_ws;
  u16* xb = (u16*)p;
  u16* Wt = (u16*)(p + (size_t)SEQ * FEAT * 2);
  u16* att = (u16*)p;
  p += (size_t)SEQ * FEAT * 2 + (size_t)F3 * FEAT * 2;
  u16* qkvb = (u16*)p;  p += (size_t)SEQ * F3 * 2;
  u16* vt   = (u16*)p;  p += (size_t)FEAT * SEQ * 2;
  u16* sc0  = (u16*)p;  p += (size_t)SEQ * SEQ * 2;   // bf16 scores (causal blocks)
  if (ws_size < (size_t)(p - (char*)d_ws)) return;

  const float scale = 0.02209708691207961f;  // 1/sqrt(2048)

  // zero d_out (att@v split-K atomically accumulates into it)
  hipMemsetAsync(d_out, 0, (size_t)SEQ * FEAT * sizeof(float), stream);

  cvt_f32_bf16<<<SEQ * FEAT / 8 / 256, 256, 0, stream>>>(x, xb, SEQ * FEAT / 8);
  transp_f2b<<<dim3(F3 / 32, FEAT / 32), dim3(32, 8), 0, stream>>>(W, F3, Wt, FEAT);
  // qkv = x @ W + b: 128x128 tiles, grid 48x32 = 1536 blocks (3 blocks/CU)
  gemmw<FEAT, FEAT, F3, 0, 1, 0, 1><<<dim3(F3 / 128, SEQ / 128), 256, 0, stream>>>(
      xb, Wt, (void*)qkvb, FEAT, b, 1.0f);
  transp_b2b<<<dim3(FEAT / 32, SEQ / 32), dim3(32, 8), 0, stream>>>(
      qkvb + 2 * FEAT, F3, vt, SEQ);
  // scores = (q @ k^T)/sqrt(F): compact triangular grid, 32*33/2 = 528 blocks
  gemmw<F3, F3, SEQ, 0, 0, 2, 0><<<dim3(32 * 33 / 2), 256, 0, stream>>>(
      qkvb, qkvb + FEAT, (void*)sc0, FEAT, nullptr, scale);
  softmax_rows<<<SEQ, 256, 0, stream>>>(sc0, att, npad);
  // out = att @ v: causal, split-K z=2 with complementary bi pairing, fp32 atomic
  gemmw<SEQ, SEQ, FEAT, 1, 0, 1, 0><<<dim3(FEAT / 128, SEQ / 128, 2), 256, 0, stream>>>(
      att, vt, (void*)out, 0, nullptr, 1.0f);
}

// Round 4
// 396.717 us; speedup vs baseline: 1.0336x; 1.0131x over previous
//
#include <hip/hip_runtime.h>
#include <cstdint>
#include <cstddef>
#include <cmath>

typedef unsigned short u16;
typedef short v8s __attribute__((ext_vector_type(8)));
typedef float v4f __attribute__((ext_vector_type(4)));

constexpr int SEQ = 4096;
constexpr int FEAT = 2048;
constexpr int F3 = 6144;

// ---------- helpers ----------

__device__ __forceinline__ u16 f2bf(float f) {
  union { float f; uint32_t u; } v; v.f = f;
  uint32_t r = v.u + 0x7FFFu + ((v.u >> 16) & 1u);  // round-to-nearest-even
  return (u16)(r >> 16);
}

__device__ __forceinline__ float bf2f(u16 s) {
  union { uint32_t u; float f; } v; v.u = ((uint32_t)s) << 16;
  return v.f;
}

// async global->LDS, 16B per lane; lds dest is wave-uniform base (HW: base+lane*16)
__device__ __forceinline__ void gld_lds16(const u16* g, u16* l) {
  __builtin_amdgcn_global_load_lds(
      (const __attribute__((address_space(1))) void*)g,
      (__attribute__((address_space(3))) void*)l, 16, 0, 0);
}

// ---------- conversion / transpose ----------

__global__ void cvt_f32_bf16(const float* __restrict__ in, u16* __restrict__ out, int n8) {
  int i = blockIdx.x * 256 + threadIdx.x;
  if (i >= n8) return;
  const float4* p = (const float4*)in + (size_t)i * 2;
  float4 a = p[0], b = p[1];
  union { u16 s[8]; uint4 v; } u;
  u.s[0] = f2bf(a.x); u.s[1] = f2bf(a.y); u.s[2] = f2bf(a.z); u.s[3] = f2bf(a.w);
  u.s[4] = f2bf(b.x); u.s[5] = f2bf(b.y); u.s[6] = f2bf(b.z); u.s[7] = f2bf(b.w);
  *(uint4*)(out + (size_t)i * 8) = u.v;
}

__global__ void transp_f2b(const float* __restrict__ in, int ldin,
                           u16* __restrict__ out, int ldout) {
  __shared__ float tile[32][33];
  int c0 = blockIdx.x * 32, r0 = blockIdx.y * 32;
  int tx = threadIdx.x, ty = threadIdx.y;
#pragma unroll
  for (int p = 0; p < 4; ++p)
    tile[ty + 8 * p][tx] = in[(size_t)(r0 + ty + 8 * p) * ldin + c0 + tx];
  __syncthreads();
#pragma unroll
  for (int p = 0; p < 4; ++p)
    out[(size_t)(c0 + ty + 8 * p) * ldout + r0 + tx] = f2bf(tile[tx][ty + 8 * p]);
}

__global__ void transp_b2b(const u16* __restrict__ in, int ldin,
                           u16* __restrict__ out, int ldout) {
  __shared__ u16 tile[32][33];
  int c0 = blockIdx.x * 32, r0 = blockIdx.y * 32;
  int tx = threadIdx.x, ty = threadIdx.y;
#pragma unroll
  for (int p = 0; p < 4; ++p)
    tile[ty + 8 * p][tx] = in[(size_t)(r0 + ty + 8 * p) * ldin + c0 + tx];
  __syncthreads();
#pragma unroll
  for (int p = 0; p < 4; ++p)
    out[(size_t)(c0 + ty + 8 * p) * ldout + r0 + tx] = tile[tx][ty + 8 * p];
}

// ---------- gemmw: C[M,N] = A[M,K] * B[N,K]^T  (bf16 in, k contiguous) ----------
// Tile 128(M)x256(N), BK=32, 256 thr = 4 waves; EACH WAVE OWNS 128x64
// (reuse 42.7 FLOP/LDS-byte vs 32 for 64x64 wave tiles: -25% LDS reads, the
// r0-r3 binding constraint). Per phase per wave: 12 ds_read_b128 -> 32 MFMA.
// LDS: single region [buf][A 128x32 | B 256x32] = 24 KiB x 3 bufs = 72 KiB
// -> 2 blocks/CU (8 waves), __launch_bounds__(256,2).
// Phase (one 32-K tile): STAGE(t+2, 6 gld_lds16/thread) | LOADA (8 ds) |
//   32 MFMA (bf preloaded) | vmcnt(6) | s_barrier | LOADB(t+1)->regs.
// Race-safety (as r3, verified): vmcnt(6) pre-barrier leaves only this
// phase's 6 stages in flight => post-barrier, tile t+1 fully in LDS for all
// waves; STAGE(t+2) overwrites tile t-1's buffer whose last reads drained
// before their wave crossed BAR(t-1).
// LDS swizzle (proven, conflicts=0): row of 32 elems = 4 chunks of 16B;
// logical chunk c at physical (c + (row>>1))&3; global source pre-rotated.
// MODE: 0 = rect grid (XCD col-major swizzle if SWZ);
//       1 = att@v flat LPT grid (512 blocks: f>>4 = descending bi, z = f&1,
//           K-range z*(bi+1)*64.., fp32 atomicAdd) - longest blocks dispatch
//           first so each CU pairs long+short causal work;
//       2 = compact causal triangular grid (bj <= bi/2), full K.

#define BARW() asm volatile("s_barrier" ::: "memory")
#define VMC6() asm volatile("s_waitcnt vmcnt(6)" ::: "memory")

#define STAGE(SB, KO) do { \
  u16* Lb = &LDSU[SB][0] + w * 512; \
  gld_lds16(pA0 + (KO), Lb); \
  gld_lds16(pA0 + (size_t)64 * LDA_ + (KO), Lb + 2048); \
  gld_lds16(pB0 + (KO), Lb + 4096); \
  gld_lds16(pB0 + (size_t)64 * LDB_ + (KO), Lb + 4096 + 2048); \
  gld_lds16(pB0 + (size_t)128 * LDB_ + (KO), Lb + 4096 + 4096); \
  gld_lds16(pB0 + (size_t)192 * LDB_ + (KO), Lb + 4096 + 6144); \
} while (0)

#define LOADA(BUF) do { _Pragma("unroll") \
  for (int mi = 0; mi < 8; ++mi) \
    af[mi] = *(const v8s*)(&LDSU[BUF][0] + (mi * 16 + lm) * 32 + lqs); \
} while (0)

#define LOADB(BUF) do { _Pragma("unroll") \
  for (int ni = 0; ni < 4; ++ni) \
    bf4[ni] = *(const v8s*)(&LDSU[BUF][0] + 4096 + (w * 64 + ni * 16 + lm) * 32 + lqs); \
} while (0)

__device__ __forceinline__ int tri_S(int v) {  // #blocks before row-block v
  const int u = v >> 1;
  return (v & 1) ? (u + 1) * (u + 1) : u * u + u;
}

template<int LDA_, int LDB_, int LDC_, int OUTMODE /*0=bf16 store, 1=fp32 atomicAdd*/,
         int ADDB, int MODE, int SWZ>
__global__ __launch_bounds__(256, 2) void gemmw(
    const u16* __restrict__ A, const u16* __restrict__ B,
    void* __restrict__ Cv, int K,
    const float* __restrict__ bias, float scale) {
  int bi, bj, ks, ke;
  if (MODE == 2) {
    // compact causal triangular grid: row-block bi (128 rows) needs
    // col-blocks bj <= bi/2 (256 cols). 272 blocks, XCD-chunked (272%8==0).
    const int b = blockIdx.x;
    const int cpx = (int)gridDim.x >> 3;
    const int s = (b & 7) * cpx + (b >> 3);
    bi = 2 * (int)sqrtf((float)s);
    while (tri_S(bi + 1) <= s) ++bi;
    while (tri_S(bi) > s) --bi;
    bj = s - tri_S(bi);
    ks = 0; ke = K;
  } else if (MODE == 1) {
    // flat LPT grid: 512 blocks, descending K (longest first)
    const int f = blockIdx.x;
    bi = ((int)gridDim.x >> 4) - 1 - (f >> 4);   // 31..0
    bj = (f >> 1) & 7;
    const int z = f & 1;
    const int kq = (bi + 1) * 64;
    ks = z ? kq : 0;  ke = ks + kq;              // nt = kq/32 >= 2
  } else {
    if (SWZ) {
      // column-major within XCD chunk: same-XCD neighbors share the B panel
      const int gx = gridDim.x, gy = gridDim.y;
      const int b = blockIdx.y * gx + blockIdx.x;
      const int cpx = (gx * gy) >> 3;            // nwg % 8 == 0
      const int s = (b & 7) * cpx + (b >> 3);
      bi = s % gy;  bj = s / gy;
    } else { bj = blockIdx.x; bi = blockIdx.y; }
    ks = 0; ke = K;
  }
  const int i0 = bi * 128, j0 = bj * 256;

  // [buf][ A: 128 rows x 32 (4096 elems) | B: 256 rows x 32 (8192 elems) ]
  __shared__ u16 LDSU[3][12288];   // 72 KiB

  const int t = threadIdx.x;
  const int w = t >> 6, l = t & 63;
  const int lm = l & 15, lq = l >> 4;
  // fragment read: physical chunk = (lq + (row>>1)) & 3; row bases are
  // multiples of 8 => (row>>1)&3 == (lm>>1)&3
  const int lqs = ((lq + (lm >> 1)) & 3) * 8;

  // staging: 24 wave-KB per tile; wave w handles instr i = w, w+4, ..., w+20.
  // instr i covers 16 rows [(i<8 ? i : i-8)*16, +16) of A (i<8) / B (i>=8);
  // lane l: row = base + (l>>2), physical chunk l&3,
  // logical chunk = ((l&3) - ((row>>1)&3)) & 3  (swizzle inverse).
  // Row deltas between a thread's instrs are 64 => same logical chunk.
  const int l2 = l >> 2;
  const int rA = w * 16 + l2;
  const int cA = ((((l & 3) - ((rA >> 1) & 3)) & 3)) * 8;
  const u16* pA0 = A + (size_t)(i0 + rA) * LDA_ + cA;
  const u16* pB0 = B + (size_t)(j0 + rA) * LDB_ + cA;   // same row pattern

  v4f acc[8][4];
#pragma unroll
  for (int a = 0; a < 8; ++a)
#pragma unroll
    for (int b2 = 0; b2 < 4; ++b2)
      acc[a][b2] = v4f{0.f, 0.f, 0.f, 0.f};

  v8s af[8], bf4[4];

  // prologue: stage tiles 0 (buf0) and 1 (buf1); vmcnt(6) -> tile0 landed
  STAGE(0, ks); STAGE(1, ks + 32);
  VMC6(); BARW();
  LOADB(0);                           // B fragments of tile 0 -> regs

  const int nt = (ke - ks) >> 5;      // >= 2 always
  int bufr = 0;
  int k2 = ks + 64;                   // k-offset of tile t+2
  for (int tt = 0; tt < nt; ++tt) {
    const int sb = (bufr + 2 >= 3) ? bufr - 1 : bufr + 2;
    const int kst = (k2 < ke) ? k2 : ks;   // clamped stages are never read
    STAGE(sb, kst);
    LOADA(bufr);                      // 8 ds_read_b128, in-phase
    __builtin_amdgcn_s_setprio(1);
#pragma unroll
    for (int mi = 0; mi < 8; ++mi)
#pragma unroll
      for (int ni = 0; ni < 4; ++ni)
        acc[mi][ni] = __builtin_amdgcn_mfma_f32_16x16x32_bf16(af[mi], bf4[ni], acc[mi][ni], 0, 0, 0);
    __builtin_amdgcn_s_setprio(0);
    VMC6(); BARW();                   // tile tt+1 landed (all waves)
    const int nb = (bufr == 2) ? 0 : bufr + 1;
    LOADB(nb);                        // B fragments of tile tt+1 -> regs
    bufr = nb;
    k2 += 32;
  }

  // epilogue: C/D layout col=lane&15, row=quad*4+reg [m89-verified]
#pragma unroll
  for (int mi = 0; mi < 8; ++mi) {
#pragma unroll
    for (int ni = 0; ni < 4; ++ni) {
      const int cc = j0 + w * 64 + ni * 16 + lm;
      const float badd = ADDB ? bias[cc] : 0.f;
#pragma unroll
      for (int r = 0; r < 4; ++r) {
        const int rr = i0 + mi * 16 + lq * 4 + r;
        if (OUTMODE == 0)
          ((u16*)Cv)[(size_t)rr * LDC_ + cc] = f2bf(acc[mi][ni][r] * scale + badd);
        else
          atomicAdd((float*)Cv + (size_t)rr * LDC_ + cc, acc[mi][ni][r]);
      }
    }
  }
}

// ---------- row softmax with causal + padding mask (single bf16 input) ----------
__global__ __launch_bounds__(256) void softmax_rows(
    const u16* __restrict__ S0,
    u16* __restrict__ att, const int* __restrict__ npad_p) {
  const int i = blockIdx.x;
  const int np = *npad_p;
  const int kend = ((i >> 7) + 1) << 7;   // 128-rounded: matches attV read range
  const u16* r0 = S0 + (size_t)i * SEQ;
  u16* arow = att + (size_t)i * SEQ;
  const int t = threadIdx.x;

  float m = -3.0e38f, s = 0.f;
  for (int j = np + t; j <= i; j += 256) {
    float v = bf2f(r0[j]);
    if (v > m) { s = s * __expf(m - v) + 1.f; m = v; }
    else       { s += __expf(v - m); }
  }
#pragma unroll
  for (int off = 32; off > 0; off >>= 1) {
    float mo = __shfl_xor(m, off);
    float so = __shfl_xor(s, off);
    float M = fmaxf(m, mo);
    s = s * __expf(m - M) + so * __expf(mo - M);
    m = M;
  }
  __shared__ float sm[4], ss[4];
  const int w = t >> 6, l = t & 63;
  if (l == 0) { sm[w] = m; ss[w] = s; }
  __syncthreads();
  const float M = fmaxf(fmaxf(sm[0], sm[1]), fmaxf(sm[2], sm[3]));
  const float Ssum = ss[0] * __expf(sm[0] - M) + ss[1] * __expf(sm[1] - M) +
                     ss[2] * __expf(sm[2] - M) + ss[3] * __expf(sm[3] - M);
  const float inv = 1.f / Ssum;  // padded rows masked to 0 below; inv unused there

  for (int j0b = t * 8; j0b < kend; j0b += 2048) {
    union { u16 s8[8]; uint4 v; } u;
#pragma unroll
    for (int q = 0; q < 8; ++q) {
      const int j = j0b + q;
      float a = 0.f;
      if (j >= np && j <= i)
        a = __expf(bf2f(r0[j]) - M) * inv;
      u.s8[q] = f2bf(a);
    }
    *(uint4*)(arow + j0b) = u.v;
  }
}

// ---------- launch ----------

extern "C" void kernel_launch(void* const* d_in, const int* in_sizes, int n_in,
                              void* d_out, int out_size, void* d_ws, size_t ws_size,
                              hipStream_t stream) {
  const float* x = (const float*)d_in[0];
  const float* W = (const float*)d_in[1];
  const float* b = (const float*)d_in[2];
  const int* npad = (const int*)d_in[3];
  float* out = (float*)d_out;

  // workspace:
  // [xb 16MB | Wt 24MB] reused as att 32MB ][ qkvb 48MB ][ vt 16MB ][ sc0 32MB ]
  char* p = (char*)d_ws;
  u16* xb = (u16*)p;
  u16* Wt = (u16*)(p + (size_t)SEQ * FEAT * 2);
  u16* att = (u16*)p;
  p += (size_t)SEQ * FEAT * 2 + (size_t)F3 * FEAT * 2;
  u16* qkvb = (u16*)p;  p += (size_t)SEQ * F3 * 2;
  u16* vt   = (u16*)p;  p += (size_t)FEAT * SEQ * 2;
  u16* sc0  = (u16*)p;  p += (size_t)SEQ * SEQ * 2;   // bf16 scores (causal blocks)
  if (ws_size < (size_t)(p - (char*)d_ws)) return;

  const float scale = 0.02209708691207961f;  // 1/sqrt(2048)

  // zero d_out (att@v split-K atomically accumulates into it)
  hipMemsetAsync(d_out, 0, (size_t)SEQ * FEAT * sizeof(float), stream);

  cvt_f32_bf16<<<SEQ * FEAT / 8 / 256, 256, 0, stream>>>(x, xb, SEQ * FEAT / 8);
  transp_f2b<<<dim3(F3 / 32, FEAT / 32), dim3(32, 8), 0, stream>>>(W, F3, Wt, FEAT);
  // qkv = x @ W + b: 128x256 tiles, grid 24x32 = 768 blocks (2 blocks/CU)
  gemmw<FEAT, FEAT, F3, 0, 1, 0, 1><<<dim3(F3 / 256, SEQ / 128), 256, 0, stream>>>(
      xb, Wt, (void*)qkvb, FEAT, b, 1.0f);
  transp_b2b<<<dim3(FEAT / 32, SEQ / 32), dim3(32, 8), 0, stream>>>(
      qkvb + 2 * FEAT, F3, vt, SEQ);
  // scores = (q @ k^T)/sqrt(F): compact triangular grid, 272 blocks
  gemmw<F3, F3, SEQ, 0, 0, 2, 0><<<dim3(272), 256, 0, stream>>>(
      qkvb, qkvb + FEAT, (void*)sc0, FEAT, nullptr, scale);
  softmax_rows<<<SEQ, 256, 0, stream>>>(sc0, att, npad);
  // out = att @ v: causal split-K=2, flat LPT grid (512 blocks = 2/CU exactly,
  // longest-K blocks dispatch first), fp32 atomicAdd
  gemmw<SEQ, SEQ, FEAT, 1, 0, 1, 0><<<dim3(512), 256, 0, stream>>>(
      att, vt, (void*)out, 0, nullptr, 1.0f);
}